// Round 10
// baseline (118.241 us; speedup 1.0000x reference)
//
#include <hip/hip_runtime.h>
#include <hip/hip_bf16.h>

#define HWC   2128      // H*W = 38*56
#define Hf    38
#define Wfv   56
#define CINv  1024
#define FPv   512       // FEAT_PLANES
#define RNUM  512
#define NCLSv 81
#define NOUT  85        // 81 cls + 4 loc
#define NBIN  49
#define KTOT  (NBIN * FPv)            // 25088
#define PARTN ((size_t)RNUM * NOUT)   // 43520

typedef short bf16x8 __attribute__((ext_vector_type(8)));
typedef float f32x4 __attribute__((ext_vector_type(4)));

static __device__ __forceinline__ unsigned short f2bf(float f) {
  __hip_bfloat16 h = __float2bfloat16(f);
  return *reinterpret_cast<unsigned short*>(&h);
}
static __device__ __forceinline__ float bflo(unsigned u) {
  return __uint_as_float((u & 0xffffu) << 16);
}
static __device__ __forceinline__ float bfhi(unsigned u) {
  return __uint_as_float(u & 0xffff0000u);
}

// ---------------------------------------------------------------------------
// Kernel 0 (fused prep): linear grid of 7200 blocks.
//   [0,2400):    Wt[bin][96][512] bf16 prepack (bin-major) + bias_mean[96]
//   [2400,2912): w_new fp32 -> bf16
//   [2912,7200): feat [b][c][hw] fp32 -> featT [b][hw][c] bf16 (32x32 tiles)
// ---------------------------------------------------------------------------
__global__ __launch_bounds__(256) void prep_kernel(
    const float* __restrict__ w_score, const float* __restrict__ b_score,
    const float* __restrict__ w_bbox, const float* __restrict__ b_bbox,
    const float* __restrict__ w_new, const float* __restrict__ feat,
    unsigned short* __restrict__ Wt, float* __restrict__ bias_mean,
    unsigned short* __restrict__ wn_bf, unsigned short* __restrict__ featT) {
  __shared__ float t[32][33];
  const int bid = blockIdx.x;
  const int tid = threadIdx.x;
  if (bid >= 2912) {
    const int tb = bid - 2912;        // 0..4287
    const int bz = tb / 2144;         // batch
    const int rem = tb - bz * 2144;   // 67 x 32 tiles
    const int hw0 = (rem % 67) * 32;
    const int c0 = (rem / 67) * 32;
    const int tx = tid & 31, ty = tid >> 5;  // 32 x 8
    const float* fb = feat + (size_t)bz * CINv * HWC;
    const int hw = hw0 + tx;
#pragma unroll
    for (int i = 0; i < 4; ++i) {
      const int c = c0 + ty * 4 + i;
      t[ty * 4 + i][tx] = (hw < HWC) ? fb[(size_t)c * HWC + hw] : 0.f;
    }
    __syncthreads();
    unsigned short* ft = featT + (size_t)bz * HWC * CINv;
#pragma unroll
    for (int i = 0; i < 4; ++i) {
      const int hwo = hw0 + ty * 4 + i;
      if (hwo < HWC) ft[(size_t)hwo * CINv + c0 + tx] = f2bf(t[tx][ty * 4 + i]);
    }
    return;
  }
  if (bid >= 2400) {
    const int i = ((bid - 2400) * 256 + tid) * 4;  // < 512*1024
    const float4 v = *(const float4*)(w_new + i);
    ushort4 o;
    o.x = f2bf(v.x); o.y = f2bf(v.y); o.z = f2bf(v.z); o.w = f2bf(v.w);
    *(ushort4*)(wn_bf + i) = o;
    return;
  }
  const int c = bid % 96;
  const int by = bid / 96;  // 0..24
  if (by == 0 && tid == 0) {
    float s = 0.f;
    if (c < NCLSv)
      for (int b = 0; b < NBIN; ++b) s += b_score[c * NBIN + b];
    else if (c < NOUT)
      for (int b = 0; b < NBIN; ++b) s += b_bbox[(c - NCLSv) * NBIN + b];
    bias_mean[c] = s * (1.0f / NBIN);
  }
  const int k0 = by * 1024 + tid * 4;
  if (k0 >= KTOT) return;
  const int bin = k0 >> 9, f = k0 & 511;
  float4 v = make_float4(0.f, 0.f, 0.f, 0.f);
  if (c < NCLSv)
    v = *(const float4*)(w_score + ((size_t)(c * NBIN + bin)) * FPv + f);
  else if (c < NOUT)
    v = *(const float4*)(w_bbox + ((size_t)((c - NCLSv) * NBIN + bin)) * FPv + f);
  ushort4 o;
  o.x = f2bf(v.x); o.y = f2bf(v.y); o.z = f2bf(v.z); o.w = f2bf(v.w);
  *(ushort4*)(Wt + ((size_t)bin * 96 + c) * FPv + f) = o;
}

// ---------------------------------------------------------------------------
// Kernel 1: MFMA GEMM: x_bf[b][hw][f] = sum_c featT[b][hw][c]*wn_bf[f][c].
// (unchanged from round 8/9)
// ---------------------------------------------------------------------------
#define BSTRIDE1 136
__global__ __launch_bounds__(256) void gemm1_mfma_kernel(
    const unsigned short* __restrict__ featT,
    const unsigned short* __restrict__ wn_bf,
    unsigned short* __restrict__ x_bf) {
  __shared__ unsigned short Bs[32 * BSTRIDE1];  // 8.7 KB
  const int tid = threadIdx.x;
  const int lane = tid & 63, wid = tid >> 6;
  const int b = blockIdx.z;
  const int f0 = blockIdx.y * 32;
  const int hwbase = blockIdx.x * 64 + wid * 16;
  const int arow = min(hwbase + (lane & 15), HWC - 1);
  const int fr_f = lane & 15;
  const int fr_k = (lane >> 4) << 3;
  const unsigned short* Ap = featT + ((size_t)b * HWC + arow) * CINv + fr_k;
  const int sr = tid >> 3;
  const int sc = (tid & 7) * 16;
  const unsigned short* Bg = wn_bf + (size_t)(f0 + sr) * CINv + sc;

  uint4 breg[2];
  bf16x8 aCur[4], aNxt[4];
  breg[0] = *(const uint4*)(Bg);
  breg[1] = *(const uint4*)(Bg + 8);
#pragma unroll
  for (int s = 0; s < 4; ++s) aCur[s] = *(const bf16x8*)(Ap + s * 32);

  f32x4 acc[2] = {};
  for (int kc = 0; kc < CINv; kc += 128) {
    __syncthreads();
    *(uint4*)&Bs[sr * BSTRIDE1 + sc] = breg[0];
    *(uint4*)&Bs[sr * BSTRIDE1 + sc + 8] = breg[1];
    const int kn = kc + 128;
    if (kn < CINv) {
      breg[0] = *(const uint4*)(Bg + kn);
      breg[1] = *(const uint4*)(Bg + kn + 8);
#pragma unroll
      for (int s = 0; s < 4; ++s) aNxt[s] = *(const bf16x8*)(Ap + kn + s * 32);
    }
    __syncthreads();
#pragma unroll
    for (int s = 0; s < 4; ++s) {
#pragma unroll
      for (int n = 0; n < 2; ++n) {
        const bf16x8 bv =
            *(const bf16x8*)&Bs[(fr_f + n * 16) * BSTRIDE1 + s * 32 + fr_k];
        acc[n] =
            __builtin_amdgcn_mfma_f32_16x16x32_bf16(aCur[s], bv, acc[n], 0, 0, 0);
      }
    }
#pragma unroll
    for (int s = 0; s < 4; ++s) aCur[s] = aNxt[s];
  }
  const int c_lo = lane & 15;
  const int rbase = hwbase + ((lane >> 4) << 2);
#pragma unroll
  for (int n = 0; n < 2; ++n) {
#pragma unroll
    for (int reg = 0; reg < 4; ++reg) {
      const int hwo = rbase + reg;
      if (hwo < HWC)
        x_bf[((size_t)b * HWC + hwo) * FPv + f0 + n * 16 + c_lo] =
            f2bf(acc[n][reg]);
    }
  }
}

// ---------------------------------------------------------------------------
// Kernel 2 (FUSED pool+gemm2): block (rt of 32 rois, bin).
// Phase A: pool 32 rois x 512 f for this bin into LDS (bitwise-identical
//          math to the old pool_kernel).
// Phase B: MFMA 32x96xK=512 against Wt[bin] (identical chunked staging and
//          accumulation order to the old gemm2_kernel).
// partial[bin][r][c] written directly; P never materialized.
// ---------------------------------------------------------------------------
#define B2STRIDE 136
__global__ __launch_bounds__(256) void pool_gemm2_kernel(
    const unsigned short* __restrict__ x_bf, const float* __restrict__ rois,
    const void* __restrict__ stride_ptr, const unsigned short* __restrict__ Wt,
    float* __restrict__ partial) {
  __shared__ unsigned int A_u[32][260];        // 32 rois x 512 bf16 (pad 520)
  __shared__ unsigned short Bs[96 * B2STRIDE]; // 96 x 128-k chunk
  __shared__ int g_ry[32][2][2];               // [roi][sy][tap] row*Wfv
  __shared__ float g_wy[32][2];
  __shared__ int g_gx[32][2][2];               // [roi][sx][tap] x index
  __shared__ float g_wx[32][2];
  __shared__ int g_base[32];                   // batch base offset (elems)

  const int tid = threadIdx.x;
  const int lane = tid & 63, wid = tid >> 6;
  const int rt = blockIdx.x;   // 0..15 (32 rois each)
  const int bin = blockIdx.y;  // 0..48
  const int ph = bin / 7, pw = bin % 7;
  const int r0 = rt * 32;

  // ---- issue B chunk-0 loads early (T14 style) ----
  int srow[3], scol[3];
#pragma unroll
  for (int g = 0; g < 3; ++g) {
    const int idx = tid * 48 + g * 16;
    srow[g] = idx >> 7;
    scol[g] = idx & 127;
  }
  const unsigned short* WtB = Wt + (size_t)bin * 96 * FPv;
  uint4 breg[6];
#pragma unroll
  for (int g = 0; g < 3; ++g) {
    const unsigned short* src = WtB + (size_t)srow[g] * FPv + scol[g];
    breg[g * 2] = *(const uint4*)src;
    breg[g * 2 + 1] = *(const uint4*)(src + 8);
  }

  // ---- geometry for 32 rois (threads 0..31) ----
  if (tid < 32) {
    const float* ro = rois + (size_t)(r0 + tid) * 5;
    float stride_f;
    {
      const int iv = ((const int*)stride_ptr)[0];
      if (iv >= 1 && iv <= 4096) stride_f = (float)iv;
      else stride_f = ((const float*)stride_ptr)[0];
    }
    const float inv = 1.0f / stride_f;
    const float y1v = ro[2] * inv, y2v = ro[4] * inv;
    const float x1v = ro[1] * inv, x2v = ro[3] * inv;
    const float bhf = fmaxf(y2v - y1v, 0.1f) * (1.0f / 7.0f);
    const float bwf = fmaxf(x2v - x1v, 0.1f) * (1.0f / 7.0f);
#pragma unroll
    for (int sy = 0; sy < 2; ++sy) {
      float yy = y1v + ((float)ph + ((float)sy + 0.5f) * 0.5f) * bhf;
      yy = fminf(fmaxf(yy, 0.f), (float)(Hf - 1));
      const float y0f = floorf(yy);
      g_ry[tid][sy][0] = (int)y0f * Wfv;
      g_ry[tid][sy][1] = min((int)y0f + 1, Hf - 1) * Wfv;
      g_wy[tid][sy] = yy - y0f;
    }
#pragma unroll
    for (int sx = 0; sx < 2; ++sx) {
      float xx = x1v + ((float)pw + ((float)sx + 0.5f) * 0.5f) * bwf;
      xx = fminf(fmaxf(xx, 0.f), (float)(Wfv - 1));
      const float x0f = floorf(xx);
      g_gx[tid][sx][0] = (int)x0f;
      g_gx[tid][sx][1] = min((int)x0f + 1, Wfv - 1);
      g_wx[tid][sx] = xx - x0f;
    }
    g_base[tid] = (int)ro[0] * (HWC * FPv);
  }
  __syncthreads();

  // ---- Phase A: pool (thread owns f-pair f2 = tid*2 for all 32 rois) ----
  const int f2 = tid * 2;
#pragma unroll 2
  for (int rr = 0; rr < 32; ++rr) {
    const unsigned short* xb = x_bf + g_base[rr];
    float a0 = 0.f, a1 = 0.f;
#pragma unroll
    for (int sy = 0; sy < 2; ++sy) {
      const int ry0 = g_ry[rr][sy][0];
      const int ry1 = g_ry[rr][sy][1];
      const float wy = g_wy[rr][sy];
      const float cy = 1.f - wy;
#pragma unroll
      for (int sx = 0; sx < 2; ++sx) {
        const int xi0 = g_gx[rr][sx][0], xi1 = g_gx[rr][sx][1];
        const float wx = g_wx[rr][sx];
        const float cx = 1.f - wx;
        const unsigned u00 = *(const unsigned*)(xb + (size_t)(ry0 + xi0) * FPv + f2);
        const unsigned u01 = *(const unsigned*)(xb + (size_t)(ry0 + xi1) * FPv + f2);
        const unsigned u10 = *(const unsigned*)(xb + (size_t)(ry1 + xi0) * FPv + f2);
        const unsigned u11 = *(const unsigned*)(xb + (size_t)(ry1 + xi1) * FPv + f2);
        const float w00 = cy * cx, w01 = cy * wx, w10 = wy * cx, w11 = wy * wx;
        a0 += w00 * bflo(u00) + w01 * bflo(u01) + w10 * bflo(u10) + w11 * bflo(u11);
        a1 += w00 * bfhi(u00) + w01 * bfhi(u01) + w10 * bfhi(u10) + w11 * bfhi(u11);
      }
    }
    const unsigned lo = f2bf(a0 * 0.25f);
    const unsigned hi = f2bf(a1 * 0.25f);
    A_u[rr][tid] = lo | (hi << 16);
  }

  // ---- Phase B: MFMA (identical order to old gemm2) ----
  const int fr_f = lane & 15;
  const int fr_k = (lane >> 4) << 3;
  const int rowfrag = wid >> 1;          // 0,0,1,1
  const int colbase = (wid & 1) * 48;    // 0 / 48
  const unsigned short* A_s =
      (const unsigned short*)A_u + (size_t)(rowfrag * 16 + fr_f) * 520 + fr_k;

  f32x4 acc[3] = {};
  for (int kc = 0; kc < FPv; kc += 128) {
    __syncthreads();  // iter0: pool done; later: prev MFMA reads done
#pragma unroll
    for (int g = 0; g < 3; ++g) {
      unsigned short* dst = &Bs[srow[g] * B2STRIDE + scol[g]];
      *(uint4*)dst = breg[g * 2];
      *(uint4*)(dst + 8) = breg[g * 2 + 1];
    }
    const int kn = kc + 128;
    if (kn < FPv) {
#pragma unroll
      for (int g = 0; g < 3; ++g) {
        const unsigned short* src = WtB + (size_t)srow[g] * FPv + kn + scol[g];
        breg[g * 2] = *(const uint4*)src;
        breg[g * 2 + 1] = *(const uint4*)(src + 8);
      }
    }
    __syncthreads();  // Bs ready
#pragma unroll
    for (int s = 0; s < 4; ++s) {
      const bf16x8 a = *(const bf16x8*)(A_s + kc + s * 32);
#pragma unroll
      for (int n = 0; n < 3; ++n) {
        const bf16x8 bv = *(const bf16x8*)
            &Bs[(colbase + n * 16 + fr_f) * B2STRIDE + s * 32 + fr_k];
        acc[n] = __builtin_amdgcn_mfma_f32_16x16x32_bf16(a, bv, acc[n], 0, 0, 0);
      }
    }
  }
  // D: col = b-row (c), row = a-row (roi): row = (lane>>4)*4 + reg
  const int c_lo = lane & 15;
  const int rr = r0 + rowfrag * 16 + ((lane >> 4) << 2);
  float* pb = partial + (size_t)bin * PARTN;
#pragma unroll
  for (int n = 0; n < 3; ++n) {
    const int c = colbase + n * 16 + c_lo;
    if (c < NOUT) {
#pragma unroll
      for (int reg = 0; reg < 4; ++reg)
        pb[(size_t)(rr + reg) * NOUT + c] = acc[n][reg];
    }
  }
}

// ---------------------------------------------------------------------------
// Kernel 3: fixed-order reduction over 49 bins + bias -> final layout.
// ---------------------------------------------------------------------------
__global__ __launch_bounds__(256) void reduce_kernel(
    const float* __restrict__ partial, const float* __restrict__ bias_mean,
    float* __restrict__ out) {
  const int g = blockIdx.x * 256 + threadIdx.x;  // 0..43519
  const int r = g / NOUT;
  const int cc = g - r * NOUT;
  float s = 0.f;
  for (int b = 0; b < NBIN; ++b) s += partial[(size_t)b * PARTN + g];
  s = s * (1.0f / NBIN) + bias_mean[cc];
  if (cc < NCLSv)
    out[(size_t)r * NCLSv + cc] = s;
  else
    out[(size_t)RNUM * NCLSv + (size_t)r * 4 + (cc - NCLSv)] = s;
}

// ---------------------------------------------------------------------------
extern "C" void kernel_launch(void* const* d_in, const int* in_sizes, int n_in,
                              void* d_out, int out_size, void* d_ws,
                              size_t ws_size, hipStream_t stream) {
  const float* rois    = (const float*)d_in[0];
  const float* feat    = (const float*)d_in[1];
  const float* w_new   = (const float*)d_in[2];
  const float* w_score = (const float*)d_in[3];
  const float* b_score = (const float*)d_in[4];
  const float* w_bbox  = (const float*)d_in[5];
  const float* b_bbox  = (const float*)d_in[6];
  const void*  stridep = d_in[7];
  float* out = (float*)d_out;

  // ws layout (256B-aligned). featT (dead after gemm1) aliases partial.
  // P region retained in layout but now unused (pool fused into gemm2).
  char* w = (char*)d_ws;
  unsigned short* x_bf = (unsigned short*)w;               // 4,358,144 B
  w += ((size_t)2 * HWC * FPv * 2 + 255) & ~(size_t)255;
  w += ((size_t)RNUM * KTOT * 2 + 255) & ~(size_t)255;     // (unused P)
  unsigned short* Wt = (unsigned short*)w;                 // 4,816,896 B
  w += ((size_t)96 * KTOT * 2 + 255) & ~(size_t)255;
  char* shared_blk = w;                                    // max(featT, partial)
  unsigned short* featT = (unsigned short*)shared_blk;     // 8,716,288 B
  float* partial = (float*)shared_blk;                     // 8,529,920 B
  w += ((size_t)2 * HWC * CINv * 2 + 255) & ~(size_t)255;
  unsigned short* wn_bf = (unsigned short*)w;              // 1,048,576 B
  w += ((size_t)FPv * CINv * 2 + 255) & ~(size_t)255;
  float* bias_mean = (float*)w;                            // 384 B

  {
    prep_kernel<<<7200, 256, 0, stream>>>(w_score, b_score, w_bbox, b_bbox,
                                          w_new, feat, Wt, bias_mean, wn_bf,
                                          featT);
  }
  {
    dim3 grid((HWC + 63) / 64, FPv / 32, 2);
    gemm1_mfma_kernel<<<grid, 256, 0, stream>>>(featT, wn_bf, x_bf);
  }
  {
    dim3 grid(RNUM / 32, NBIN);
    pool_gemm2_kernel<<<grid, 256, 0, stream>>>(x_bf, rois, stridep, Wt,
                                                partial);
  }
  {
    reduce_kernel<<<(RNUM * NOUT) / 256, 256, 0, stream>>>(partial, bias_mean,
                                                           out);
  }
}

// Round 12
// 103.157 us; speedup vs baseline: 1.1462x; 1.1462x over previous
//
#include <hip/hip_runtime.h>
#include <hip/hip_bf16.h>

#define HWC   2128      // H*W = 38*56
#define Hf    38
#define Wfv   56
#define CINv  1024
#define FPv   512       // FEAT_PLANES
#define RNUM  512
#define NCLSv 81
#define NOUT  85        // 81 cls + 4 loc
#define NBIN  49
#define KTOT  (NBIN * FPv)            // 25088
#define PARTN ((size_t)RNUM * NOUT)   // 43520

typedef short bf16x8 __attribute__((ext_vector_type(8)));
typedef float f32x4 __attribute__((ext_vector_type(4)));

static __device__ __forceinline__ unsigned short f2bf(float f) {
  __hip_bfloat16 h = __float2bfloat16(f);
  return *reinterpret_cast<unsigned short*>(&h);
}
static __device__ __forceinline__ float bflo(unsigned u) {
  return __uint_as_float((u & 0xffffu) << 16);
}
static __device__ __forceinline__ float bfhi(unsigned u) {
  return __uint_as_float(u & 0xffff0000u);
}

// ---------------------------------------------------------------------------
// Kernel 0 (fused prep): linear grid of 7200 blocks.
//   [0,2400):    Wt[bin][96][512] bf16 prepack (bin-major) + bias_mean[96]
//   [2400,2912): w_new fp32 -> bf16
//   [2912,7200): feat [b][c][hw] fp32 -> featT [b][hw][c] bf16 (32x32 tiles)
// ---------------------------------------------------------------------------
__global__ __launch_bounds__(256) void prep_kernel(
    const float* __restrict__ w_score, const float* __restrict__ b_score,
    const float* __restrict__ w_bbox, const float* __restrict__ b_bbox,
    const float* __restrict__ w_new, const float* __restrict__ feat,
    unsigned short* __restrict__ Wt, float* __restrict__ bias_mean,
    unsigned short* __restrict__ wn_bf, unsigned short* __restrict__ featT) {
  __shared__ float t[32][33];
  const int bid = blockIdx.x;
  const int tid = threadIdx.x;
  if (bid >= 2912) {
    const int tb = bid - 2912;        // 0..4287
    const int bz = tb / 2144;         // batch
    const int rem = tb - bz * 2144;   // 67 x 32 tiles
    const int hw0 = (rem % 67) * 32;
    const int c0 = (rem / 67) * 32;
    const int tx = tid & 31, ty = tid >> 5;  // 32 x 8
    const float* fb = feat + (size_t)bz * CINv * HWC;
    const int hw = hw0 + tx;
#pragma unroll
    for (int i = 0; i < 4; ++i) {
      const int c = c0 + ty * 4 + i;
      t[ty * 4 + i][tx] = (hw < HWC) ? fb[(size_t)c * HWC + hw] : 0.f;
    }
    __syncthreads();
    unsigned short* ft = featT + (size_t)bz * HWC * CINv;
#pragma unroll
    for (int i = 0; i < 4; ++i) {
      const int hwo = hw0 + ty * 4 + i;
      if (hwo < HWC) ft[(size_t)hwo * CINv + c0 + tx] = f2bf(t[tx][ty * 4 + i]);
    }
    return;
  }
  if (bid >= 2400) {
    const int i = ((bid - 2400) * 256 + tid) * 4;  // < 512*1024
    const float4 v = *(const float4*)(w_new + i);
    ushort4 o;
    o.x = f2bf(v.x); o.y = f2bf(v.y); o.z = f2bf(v.z); o.w = f2bf(v.w);
    *(ushort4*)(wn_bf + i) = o;
    return;
  }
  const int c = bid % 96;
  const int by = bid / 96;  // 0..24
  if (by == 0 && tid == 0) {
    float s = 0.f;
    if (c < NCLSv)
      for (int b = 0; b < NBIN; ++b) s += b_score[c * NBIN + b];
    else if (c < NOUT)
      for (int b = 0; b < NBIN; ++b) s += b_bbox[(c - NCLSv) * NBIN + b];
    bias_mean[c] = s * (1.0f / NBIN);
  }
  const int k0 = by * 1024 + tid * 4;
  if (k0 >= KTOT) return;
  const int bin = k0 >> 9, f = k0 & 511;
  float4 v = make_float4(0.f, 0.f, 0.f, 0.f);
  if (c < NCLSv)
    v = *(const float4*)(w_score + ((size_t)(c * NBIN + bin)) * FPv + f);
  else if (c < NOUT)
    v = *(const float4*)(w_bbox + ((size_t)((c - NCLSv) * NBIN + bin)) * FPv + f);
  ushort4 o;
  o.x = f2bf(v.x); o.y = f2bf(v.y); o.z = f2bf(v.z); o.w = f2bf(v.w);
  *(ushort4*)(Wt + ((size_t)bin * 96 + c) * FPv + f) = o;
}

// ---------------------------------------------------------------------------
// Kernel 1: MFMA GEMM v4b: x_bf[b][hw][f] = sum_c featT[b][hw][c]*wn_bf[f][c].
// Grid 544 = 34 hwg x 8 fg x 2 b, bijective XCD swizzle (544 = 8 x 68), hw
// decoded slowest so each XCD owns a contiguous ~1.3MB featT slice (L2-fit).
// Block = 512 thr = 8 waves (4 whw x 2 wf) of 16hw x 32f => 64hw x 64f tile.
// BK=128; B staged in LDS (issue-early/write-late reg dbuf); A prefetched.
// Per-output accumulation order identical to v2/v3 (bitwise-same result).
// ---------------------------------------------------------------------------
#define BSTRIDE1 136
__global__ __launch_bounds__(512) void gemm1_mfma_kernel(
    const unsigned short* __restrict__ featT,
    const unsigned short* __restrict__ wn_bf,
    unsigned short* __restrict__ x_bf) {
  __shared__ unsigned short Bs[64 * BSTRIDE1];  // 17.4 KB
  const int tid = threadIdx.x;
  const int lane = tid & 63, wid = tid >> 6;  // 8 waves
  // XCD-bijective swizzle: nwg = 544 = 8 xcd * 68
  const int orig = blockIdx.x;
  const int wgid = (orig & 7) * 68 + (orig >> 3);
  // decode hw slowest: 16 inner = 8 fg x 2 b
  const int hwg = wgid >> 4;        // 0..33
  const int rem = wgid & 15;
  const int fg = rem >> 1;          // 0..7
  const int b = rem & 1;
  const int f0 = fg * 64;           // block covers f0..f0+63 (< 512)
  const int whw = wid & 3, wf = wid >> 2;
  const int hwbase = hwg * 64 + whw * 16;
  const int arow = min(hwbase + (lane & 15), HWC - 1);
  const int fr_f = lane & 15;
  const int fr_k = (lane >> 4) << 3;
  const unsigned short* Ap = featT + ((size_t)b * HWC + arow) * CINv + fr_k;
  // B staging: 64 rows x 128 cols; thread t -> row t>>3, cols (t&7)*16..+15
  const int sr = tid >> 3;
  const int sc = (tid & 7) * 16;
  const unsigned short* Bg = wn_bf + (size_t)(f0 + sr) * CINv + sc;

  uint4 breg[2];
  bf16x8 aCur[4], aNxt[4];
  breg[0] = *(const uint4*)(Bg);
  breg[1] = *(const uint4*)(Bg + 8);
#pragma unroll
  for (int s = 0; s < 4; ++s) aCur[s] = *(const bf16x8*)(Ap + s * 32);

  f32x4 acc[2] = {};
  for (int kc = 0; kc < CINv; kc += 128) {
    __syncthreads();
    *(uint4*)&Bs[sr * BSTRIDE1 + sc] = breg[0];
    *(uint4*)&Bs[sr * BSTRIDE1 + sc + 8] = breg[1];
    const int kn = kc + 128;
    if (kn < CINv) {
      breg[0] = *(const uint4*)(Bg + kn);
      breg[1] = *(const uint4*)(Bg + kn + 8);
#pragma unroll
      for (int s = 0; s < 4; ++s) aNxt[s] = *(const bf16x8*)(Ap + kn + s * 32);
    }
    __syncthreads();
#pragma unroll
    for (int s = 0; s < 4; ++s) {
#pragma unroll
      for (int n = 0; n < 2; ++n) {
        const bf16x8 bv = *(const bf16x8*)
            &Bs[(wf * 32 + n * 16 + fr_f) * BSTRIDE1 + s * 32 + fr_k];
        acc[n] =
            __builtin_amdgcn_mfma_f32_16x16x32_bf16(aCur[s], bv, acc[n], 0, 0, 0);
      }
    }
#pragma unroll
    for (int s = 0; s < 4; ++s) aCur[s] = aNxt[s];
  }
  // D: col = lane&15 (f), row = (lane>>4)*4 + reg (hw)
  const int c_lo = lane & 15;
  const int rbase = hwbase + ((lane >> 4) << 2);
#pragma unroll
  for (int n = 0; n < 2; ++n) {
#pragma unroll
    for (int reg = 0; reg < 4; ++reg) {
      const int hwo = rbase + reg;
      if (hwo < HWC)
        x_bf[((size_t)b * HWC + hwo) * FPv + f0 + wf * 32 + n * 16 + c_lo] =
            f2bf(acc[n][reg]);
    }
  }
}

// ---------------------------------------------------------------------------
// Kernel 2: PSRoI pooling -> P[bin][r][f] (bin-major, bf16 pairs).
// Grid (512 rois, 7 ph).  (R9 version, verified)
// ---------------------------------------------------------------------------
__global__ __launch_bounds__(256) void pool_kernel(
    const unsigned short* __restrict__ x_bf, const float* __restrict__ rois,
    const void* __restrict__ stride_ptr, unsigned int* __restrict__ P_u) {
  __shared__ int ys0[2], ys1[2];
  __shared__ float wys[2];
  __shared__ int xs0[14], xs1[14];
  __shared__ float wxs[14];
  const int tid = threadIdx.x;
  const int r = blockIdx.x;
  const int ph = blockIdx.y;  // 0..6
  const float* ro = rois + (size_t)r * 5;

  float stride_f;
  {
    const int iv = ((const int*)stride_ptr)[0];
    if (iv >= 1 && iv <= 4096) stride_f = (float)iv;
    else stride_f = ((const float*)stride_ptr)[0];
  }
  const float inv = 1.0f / stride_f;

  if (tid < 2) {
    const float y1v = ro[2] * inv, y2v = ro[4] * inv;
    const float bhf = fmaxf(y2v - y1v, 0.1f) * (1.0f / 7.0f);
    const int sy = tid;
    float yy = y1v + ((float)ph + ((float)sy + 0.5f) * 0.5f) * bhf;
    yy = fminf(fmaxf(yy, 0.f), (float)(Hf - 1));
    const float y0f = floorf(yy);
    ys0[tid] = (int)y0f;
    ys1[tid] = min((int)y0f + 1, Hf - 1);
    wys[tid] = yy - y0f;
  } else if (tid >= 64 && tid < 78) {
    const int s = tid - 64;
    const float x1v = ro[1] * inv, x2v = ro[3] * inv;
    const float bwf = fmaxf(x2v - x1v, 0.1f) * (1.0f / 7.0f);
    const int pw = s >> 1, sx = s & 1;
    float xx = x1v + ((float)pw + ((float)sx + 0.5f) * 0.5f) * bwf;
    xx = fminf(fmaxf(xx, 0.f), (float)(Wfv - 1));
    const float x0f = floorf(xx);
    xs0[s] = (int)x0f;
    xs1[s] = min((int)x0f + 1, Wfv - 1);
    wxs[s] = xx - x0f;
  }
  __syncthreads();

  const int b = (int)ro[0];
  const unsigned short* xb = x_bf + (size_t)b * HWC * FPv;
  const int f2 = tid * 2;

  float acc[7][2] = {};
#pragma unroll
  for (int sy = 0; sy < 2; ++sy) {
    const int ry0 = ys0[sy] * Wfv;
    const int ry1 = ys1[sy] * Wfv;
    const float wy = wys[sy];
    const float cy = 1.f - wy;
#pragma unroll
    for (int pwsx = 0; pwsx < 14; ++pwsx) {
      const int xi0 = xs0[pwsx], xi1 = xs1[pwsx];
      const float wx = wxs[pwsx];
      const float cx = 1.f - wx;
      const unsigned u00 = *(const unsigned*)(xb + (size_t)(ry0 + xi0) * FPv + f2);
      const unsigned u01 = *(const unsigned*)(xb + (size_t)(ry0 + xi1) * FPv + f2);
      const unsigned u10 = *(const unsigned*)(xb + (size_t)(ry1 + xi0) * FPv + f2);
      const unsigned u11 = *(const unsigned*)(xb + (size_t)(ry1 + xi1) * FPv + f2);
      const float w00 = cy * cx, w01 = cy * wx, w10 = wy * cx, w11 = wy * wx;
      const int pw = pwsx >> 1;
      acc[pw][0] += w00 * bflo(u00) + w01 * bflo(u01) + w10 * bflo(u10) + w11 * bflo(u11);
      acc[pw][1] += w00 * bfhi(u00) + w01 * bfhi(u01) + w10 * bfhi(u10) + w11 * bfhi(u11);
    }
  }
  // bin-major: P[bin][r][f], bin = ph*7+pw
#pragma unroll
  for (int pw = 0; pw < 7; ++pw) {
    const unsigned lo = f2bf(acc[pw][0] * 0.25f);
    const unsigned hi = f2bf(acc[pw][1] * 0.25f);
    P_u[((size_t)(ph * 7 + pw) * RNUM + r) * (FPv / 2) + tid] = lo | (hi << 16);
  }
}

// ---------------------------------------------------------------------------
// Kernel 3: MFMA GEMM, split-K by bin: partial[bin][r][c] = P[r]·Wt[c] (bin).
// Bin-major operands (R9 version, verified).
// ---------------------------------------------------------------------------
#define B2STRIDE 136
__global__ __launch_bounds__(256) void gemm2_kernel(
    const unsigned short* __restrict__ P, const unsigned short* __restrict__ Wt,
    float* __restrict__ partial) {
  __shared__ unsigned short Bs[96 * B2STRIDE];
  const int tid = threadIdx.x;
  const int lane = tid & 63, wid = tid >> 6;
  const int rt = blockIdx.x;   // 0..7
  const int bin = blockIdx.y;  // 0..48
  const int arow = rt * 64 + wid * 16 + (lane & 15);
  const int fr_f = lane & 15;
  const int fr_k = (lane >> 4) << 3;
  const unsigned short* Ap = P + ((size_t)bin * RNUM + arow) * FPv + fr_k;
  int srow[3], scol[3];
#pragma unroll
  for (int g = 0; g < 3; ++g) {
    const int idx = tid * 48 + g * 16;
    srow[g] = idx >> 7;
    scol[g] = idx & 127;
  }
  const unsigned short* WtB = Wt + (size_t)bin * 96 * FPv;

  uint4 breg[6];
  bf16x8 aCur[4], aNxt[4];
#pragma unroll
  for (int g = 0; g < 3; ++g) {
    const unsigned short* src = WtB + (size_t)srow[g] * FPv + scol[g];
    breg[g * 2] = *(const uint4*)src;
    breg[g * 2 + 1] = *(const uint4*)(src + 8);
  }
#pragma unroll
  for (int s = 0; s < 4; ++s) aCur[s] = *(const bf16x8*)(Ap + s * 32);

  f32x4 acc[6] = {};
  for (int kc = 0; kc < FPv; kc += 128) {
    __syncthreads();
#pragma unroll
    for (int g = 0; g < 3; ++g) {
      unsigned short* dst = &Bs[srow[g] * B2STRIDE + scol[g]];
      *(uint4*)dst = breg[g * 2];
      *(uint4*)(dst + 8) = breg[g * 2 + 1];
    }
    const int kn = kc + 128;
    if (kn < FPv) {
#pragma unroll
      for (int g = 0; g < 3; ++g) {
        const unsigned short* src = WtB + (size_t)srow[g] * FPv + kn + scol[g];
        breg[g * 2] = *(const uint4*)src;
        breg[g * 2 + 1] = *(const uint4*)(src + 8);
      }
#pragma unroll
      for (int s = 0; s < 4; ++s) aNxt[s] = *(const bf16x8*)(Ap + kn + s * 32);
    }
    __syncthreads();
#pragma unroll
    for (int s = 0; s < 4; ++s) {
#pragma unroll
      for (int n = 0; n < 6; ++n) {
        const bf16x8 bv =
            *(const bf16x8*)&Bs[(fr_f + n * 16) * B2STRIDE + s * 32 + fr_k];
        acc[n] =
            __builtin_amdgcn_mfma_f32_16x16x32_bf16(aCur[s], bv, acc[n], 0, 0, 0);
      }
    }
#pragma unroll
    for (int s = 0; s < 4; ++s) aCur[s] = aNxt[s];
  }
  const int c_lo = lane & 15;
  const int rr = rt * 64 + wid * 16 + ((lane >> 4) << 2);
  float* pb = partial + (size_t)bin * PARTN;
#pragma unroll
  for (int n = 0; n < 6; ++n) {
    const int c = n * 16 + c_lo;
    if (c < NOUT) {
#pragma unroll
      for (int reg = 0; reg < 4; ++reg)
        pb[(size_t)(rr + reg) * NOUT + c] = acc[n][reg];
    }
  }
}

// ---------------------------------------------------------------------------
// Kernel 4: fixed-order reduction over 49 bins + bias -> final layout.
// ---------------------------------------------------------------------------
__global__ __launch_bounds__(256) void reduce_kernel(
    const float* __restrict__ partial, const float* __restrict__ bias_mean,
    float* __restrict__ out) {
  const int g = blockIdx.x * 256 + threadIdx.x;  // 0..43519
  const int r = g / NOUT;
  const int cc = g - r * NOUT;
  float s = 0.f;
  for (int b = 0; b < NBIN; ++b) s += partial[(size_t)b * PARTN + g];
  s = s * (1.0f / NBIN) + bias_mean[cc];
  if (cc < NCLSv)
    out[(size_t)r * NCLSv + cc] = s;
  else
    out[(size_t)RNUM * NCLSv + (size_t)r * 4 + (cc - NCLSv)] = s;
}

// ---------------------------------------------------------------------------
extern "C" void kernel_launch(void* const* d_in, const int* in_sizes, int n_in,
                              void* d_out, int out_size, void* d_ws,
                              size_t ws_size, hipStream_t stream) {
  const float* rois    = (const float*)d_in[0];
  const float* feat    = (const float*)d_in[1];
  const float* w_new   = (const float*)d_in[2];
  const float* w_score = (const float*)d_in[3];
  const float* b_score = (const float*)d_in[4];
  const float* w_bbox  = (const float*)d_in[5];
  const float* b_bbox  = (const float*)d_in[6];
  const void*  stridep = d_in[7];
  float* out = (float*)d_out;

  // ws layout (256B-aligned). featT (dead after gemm1) aliases partial.
  char* w = (char*)d_ws;
  unsigned short* x_bf = (unsigned short*)w;               // 4,358,144 B
  w += ((size_t)2 * HWC * FPv * 2 + 255) & ~(size_t)255;
  unsigned short* P = (unsigned short*)w;                  // 25,690,112 B
  w += ((size_t)RNUM * KTOT * 2 + 255) & ~(size_t)255;
  unsigned short* Wt = (unsigned short*)w;                 // 4,816,896 B
  w += ((size_t)96 * KTOT * 2 + 255) & ~(size_t)255;
  char* shared_blk = w;                                    // max(featT, partial)
  unsigned short* featT = (unsigned short*)shared_blk;     // 8,716,288 B
  float* partial = (float*)shared_blk;                     // 8,529,920 B
  w += ((size_t)2 * HWC * CINv * 2 + 255) & ~(size_t)255;
  unsigned short* wn_bf = (unsigned short*)w;              // 1,048,576 B
  w += ((size_t)FPv * CINv * 2 + 255) & ~(size_t)255;
  float* bias_mean = (float*)w;                            // 384 B

  {
    prep_kernel<<<7200, 256, 0, stream>>>(w_score, b_score, w_bbox, b_bbox,
                                          w_new, feat, Wt, bias_mean, wn_bf,
                                          featT);
  }
  {
    // 544 blocks = 34 hwg x 8 fg x 2 b = 8 XCD x 68
    gemm1_mfma_kernel<<<544, 512, 0, stream>>>(featT, wn_bf, x_bf);
  }
  {
    dim3 grid(RNUM, 7);
    pool_kernel<<<grid, 256, 0, stream>>>(x_bf, rois, stridep,
                                          (unsigned int*)P);
  }
  {
    dim3 grid(RNUM / 64, NBIN);
    gemm2_kernel<<<grid, 256, 0, stream>>>(P, Wt, partial);
  }
  {
    reduce_kernel<<<(RNUM * NOUT) / 256, 256, 0, stream>>>(partial, bias_mean,
                                                           out);
  }
}